// Round 6
// baseline (133.948 us; speedup 1.0000x reference)
//
#include <hip/hip_runtime.h>

// SQDDPG mixer, MI355X. Round 6: single M=128 sweep (both R5 passes fused):
// every W1b/W2 B-fragment loaded once per block (L2 traffic halved), h1 in
// 64 KB LDS, 2 blocks/CU, (256,2) so no spill (R4 lesson). Pack fused into
// prep launch.
//
// Frozen validated facts (R2/R3/R5 passes): threefry partitionable,
// bits=o0^o1, counter (0, b*128+n); stable ranks; coalition slot j <-
// qs[inv_l[j]]; output agent n reads prefix-row pos_l[n]; A/B frag formulas
// (mt-width generalized 4->8 symmetrically on scatter+read).

#define A_N   8
#define NA_N  16
#define S_N   16
#define SD    256
#define EMB   256
#define B_TOT 1024

typedef __bf16 bf16x8 __attribute__((ext_vector_type(8)));
typedef float  f32x4  __attribute__((ext_vector_type(4)));

__device__ __forceinline__ f32x4 splat4(float v) {
  f32x4 x; x[0] = v; x[1] = v; x[2] = v; x[3] = v; return x;
}
__device__ __forceinline__ bf16x8 zero8() {
  bf16x8 z;
#pragma unroll
  for (int j = 0; j < 8; ++j) z[j] = (__bf16)0.0f;
  return z;
}

// ---------------------------------------------------------------------------
// JAX threefry2x32, key = (0, 42); partitionable draw: bits = o0 ^ o1.
// ---------------------------------------------------------------------------
__device__ __forceinline__ float jax_uniform(unsigned idx) {
  const unsigned ks0 = 0u, ks1 = 42u, ks2 = 0x1BD11BDAu ^ 42u;
  unsigned x0 = 0u + ks0;
  unsigned x1 = idx + ks1;
#define TF_RND(r) { x0 += x1; x1 = (x1 << (r)) | (x1 >> (32 - (r))); x1 ^= x0; }
  TF_RND(13) TF_RND(15) TF_RND(26) TF_RND(6)  x0 += ks1; x1 += ks2 + 1u;
  TF_RND(17) TF_RND(29) TF_RND(16) TF_RND(24) x0 += ks2; x1 += ks0 + 2u;
  TF_RND(13) TF_RND(15) TF_RND(26) TF_RND(6)  x0 += ks0; x1 += ks1 + 3u;
  TF_RND(17) TF_RND(29) TF_RND(16) TF_RND(24) x0 += ks1; x1 += ks2 + 4u;
  TF_RND(13) TF_RND(15) TF_RND(26) TF_RND(6)  x0 += ks2; x1 += ks0 + 5u;
#undef TF_RND
  const unsigned bits = x0 ^ x1;
  return __uint_as_float((bits >> 9) | 0x3F800000u) - 1.0f;
}

// ---------------------------------------------------------------------------
// Fused prep (blocks 0..511: 2 b's each) + weight pack (blocks 512..559).
// ---------------------------------------------------------------------------
__global__ __launch_bounds__(256) void prep_pack_kernel(
    const float* __restrict__ states, const float* __restrict__ W1,
    const float* __restrict__ b1, const float* __restrict__ W2,
    const float* __restrict__ Vw1, const float* __restrict__ Vb1,
    const float* __restrict__ Vw2, const float* __restrict__ Vb2,
    float* __restrict__ sW, float* __restrict__ vout,
    __bf16* __restrict__ W1b_bf, __bf16* __restrict__ W2_bf) {
  const int n = threadIdx.x;

  if (blockIdx.x >= 512) {
    // ---- pack path: bf16 B-fragment order (frozen formula) ----
    const int ts = (blockIdx.x - 512) * 256 + n;    // 0..12287
    if (ts < 4096) {                                // W1 bottom: t=0..3
      const int t = ts >> 10, rem = ts & 1023, u = rem >> 6, L = rem & 63;
      const int q = L >> 4, l15 = L & 15;
#pragma unroll
      for (int j = 0; j < 8; ++j) {
        const int k = t * 32 + q * 8 + j, nn = u * 16 + l15;
        W1b_bf[ts * 8 + j] = (__bf16)W1[(SD + k) * EMB + nn];
      }
    } else {                                        // W2: t=0..7
      const int ts2 = ts - 4096;
      const int t = ts2 >> 10, rem = ts2 & 1023, u = rem >> 6, L = rem & 63;
      const int q = L >> 4, l15 = L & 15;
#pragma unroll
      for (int j = 0; j < 8; ++j) {
        const int k = t * 32 + q * 8 + j, nn = u * 16 + l15;
        W2_bf[ts2 * 8 + j] = (__bf16)W2[k * EMB + nn];
      }
    }
    return;
  }

  // ---- prep path: 2 b's per block ----
  __shared__ float st_l[2][SD];
  __shared__ float red_l[2][4];
  const int b0 = blockIdx.x * 2;

#pragma unroll
  for (int i = 0; i < 2; ++i) st_l[i][n] = states[(b0 + i) * SD + n];
  __syncthreads();

  float aS[2], aV[2];
  const float b1n = b1[n], vb1n = Vb1[n];
#pragma unroll
  for (int i = 0; i < 2; ++i) { aS[i] = b1n; aV[i] = vb1n; }

#pragma unroll 8
  for (int k = 0; k < SD; ++k) {
    const float wv = W1[k * EMB + n];
    const float vw = Vw1[k * EMB + n];
#pragma unroll
    for (int i = 0; i < 2; ++i) {
      const float s = st_l[i][k];
      aS[i] = fmaf(s, wv, aS[i]);
      aV[i] = fmaf(s, vw, aV[i]);
    }
  }
#pragma unroll
  for (int i = 0; i < 2; ++i) sW[(b0 + i) * EMB + n] = aS[i];

  const float vw2 = Vw2[n];
#pragma unroll
  for (int i = 0; i < 2; ++i) {
    float c = fmaxf(aV[i], 0.f) * vw2;
#pragma unroll
    for (int off = 32; off; off >>= 1) c += __shfl_down(c, off);
    if ((n & 63) == 0) red_l[i][n >> 6] = c;
  }
  __syncthreads();
  if (n < 2)
    vout[b0 + n] = red_l[n][0] + red_l[n][1] + red_l[n][2] + red_l[n][3] + Vb2[0];
}

// ---------------------------------------------------------------------------
// Main: 1024 blocks (one per b), 256 threads = 4 waves. ONE M=128 sweep
// (all 16 samples): mt = 0..7 row-tiles; every B-fragment loaded once.
// Column work still split in two sequential un-halves (acc[8][2] live).
// ---------------------------------------------------------------------------
__global__ __launch_bounds__(256, 2) void main_kernel(
    const float* __restrict__ agent_qs, const float* __restrict__ b2g,
    const float* __restrict__ W3, const float* __restrict__ b3,
    const float* __restrict__ sW, const float* __restrict__ vv,
    const __bf16* __restrict__ W1b_bf, const __bf16* __restrict__ W2_bf,
    float* __restrict__ out) {
  __shared__ bf16x8 h1_l[64 * 64];      // 64 KB: layer2 A-frags (M=128,K=256)
  __shared__ __attribute__((aligned(16))) __bf16 qs_bf[A_N * NA_N];
  __shared__ float u_l[128];
  __shared__ int   inv_l[128];          // inv_l[s*8+a] = rank of agent a
  __shared__ int   pos_l[128];          // pos_l[s*8+r] = agent with rank r
  __shared__ float adv_part[4][128];
  __shared__ float marg_l[128];         // marginal[s*8 + prefix-row]

  const int b = blockIdx.x;
  const int n = threadIdx.x;
  const int w = n >> 6, L = n & 63, q = L >> 4, l15 = L & 15;

  if (n < 128) {
    qs_bf[n] = (__bf16)agent_qs[b * 128 + n];
    u_l[n] = jax_uniform((unsigned)(b * 128 + n));
  }
  __syncthreads();

  if (n < 128) {
    const int s = n >> 3, a = n & 7;
    const float u = u_l[n];
    int r = 0;
#pragma unroll
    for (int a2 = 0; a2 < A_N; ++a2) {
      const float u2 = u_l[s * 8 + a2];
      r += (u2 < u || (u2 == u && a2 < a)) ? 1 : 0;
    }
    inv_l[n] = r;
    pos_l[s * 8 + r] = a;
  }
  __syncthreads();

  const int i_pref  = l15 & 7;     // prefix length of this lane's A-row
  const int sl_half = l15 >> 3;    // which s within the mt pair
  const int jq      = q >> 1;      // jcoal low bit
  const int na0     = (q & 1) * 8; // action sub-block

  // ---- layer 1: (128x128) @ W1b (128x256), C init sW[col]; 2 un-halves ---
#pragma unroll 1
  for (int nh = 0; nh < 2; ++nh) {
    f32x4 acc[8][2];
#pragma unroll
    for (int i = 0; i < 2; ++i) {
      const float sv = sW[b * EMB + (w * 4 + nh * 2 + i) * 16 + l15];
#pragma unroll
      for (int mt = 0; mt < 8; ++mt) acc[mt][i] = splat4(sv);
    }
#pragma unroll
    for (int t = 0; t < 4; ++t) {
      const int jcoal = t * 2 + jq;
      const bool on = (jcoal <= i_pref);
      bf16x8 bfr[2];
#pragma unroll
      for (int i = 0; i < 2; ++i)
        bfr[i] = *(const bf16x8*)
            &W1b_bf[((t * 16 + w * 4 + nh * 2 + i) * 64 + L) * 8];
#pragma unroll
      for (int mt = 0; mt < 8; ++mt) {
        const int ag = inv_l[(mt * 2 + sl_half) * 8 + jcoal];
        const bf16x8 qv = *(const bf16x8*)&qs_bf[ag * NA_N + na0];
        const bf16x8 af = on ? qv : zero8();
#pragma unroll
        for (int i = 0; i < 2; ++i)
          acc[mt][i] = __builtin_amdgcn_mfma_f32_16x16x32_bf16(
              af, bfr[i], acc[mt][i], 0, 0, 0);
      }
    }
    // relu -> bf16 scatter into layer2 A-frag layout (mt-width 8)
    __bf16* h1e = (__bf16*)h1_l;
#pragma unroll
    for (int i = 0; i < 2; ++i) {
      const int c = (w * 4 + nh * 2 + i) * 16 + l15;
      const int t2 = c >> 5, q2 = (c >> 3) & 3, j2 = l15 & 7;
#pragma unroll
      for (int mt = 0; mt < 8; ++mt) {
#pragma unroll
        for (int r = 0; r < 4; ++r) {
          const float v = fmaxf(acc[mt][i][r], 0.f);
          h1e[(((t2 * 8 + mt) * 64) + q2 * 16 + q * 4 + r) * 8 + j2] =
              (__bf16)v;
        }
      }
    }
  }
  __syncthreads();

  // ---- layer 2 + layer 3 partials: 2 un-halves, psum across halves ----
  float psum[8][4];
#pragma unroll
  for (int mt = 0; mt < 8; ++mt)
#pragma unroll
    for (int r = 0; r < 4; ++r) psum[mt][r] = 0.f;

#pragma unroll 1
  for (int nh = 0; nh < 2; ++nh) {
    f32x4 acc[8][2];
#pragma unroll
    for (int i = 0; i < 2; ++i) {
      const float bv = b2g[(w * 4 + nh * 2 + i) * 16 + l15];
#pragma unroll
      for (int mt = 0; mt < 8; ++mt) acc[mt][i] = splat4(bv);
    }
#pragma unroll 2
    for (int t = 0; t < 8; ++t) {
      bf16x8 bfr[2];
#pragma unroll
      for (int i = 0; i < 2; ++i)
        bfr[i] = *(const bf16x8*)
            &W2_bf[((t * 16 + w * 4 + nh * 2 + i) * 64 + L) * 8];
#pragma unroll
      for (int mt = 0; mt < 8; ++mt) {
        const bf16x8 af = h1_l[(t * 8 + mt) * 64 + L];
#pragma unroll
        for (int i = 0; i < 2; ++i)
          acc[mt][i] = __builtin_amdgcn_mfma_f32_16x16x32_bf16(
              af, bfr[i], acc[mt][i], 0, 0, 0);
      }
    }
#pragma unroll
    for (int i = 0; i < 2; ++i) {
      const float w3v = W3[(w * 4 + nh * 2 + i) * 16 + l15];
#pragma unroll
      for (int mt = 0; mt < 8; ++mt)
#pragma unroll
        for (int r = 0; r < 4; ++r)
          psum[mt][r] = fmaf(fmaxf(acc[mt][i][r], 0.f), w3v, psum[mt][r]);
    }
  }

  // ---- reduce 16 cols per quad, combine waves via LDS ----
#pragma unroll
  for (int mt = 0; mt < 8; ++mt) {
#pragma unroll
    for (int r = 0; r < 4; ++r) {
      float sum = psum[mt][r];
#pragma unroll
      for (int off = 1; off < 16; off <<= 1) sum += __shfl_xor(sum, off);
      if (l15 == 0) adv_part[w][mt * 16 + q * 4 + r] = sum;
    }
  }
  __syncthreads();
  if (n < 128)
    marg_l[n] = adv_part[0][n] + adv_part[1][n] +
                adv_part[2][n] + adv_part[3][n];
  __syncthreads();

  // ---- gather: agent a reads prefix-row pos_l[s*8+a] (validated) ----
  if (n < A_N) {
    float sh = 0.f;
#pragma unroll
    for (int s = 0; s < S_N; ++s) sh += marg_l[s * 8 + pos_l[s * 8 + n]];
    out[b * A_N + n] = sh * (1.f / 16.f) + b3[0] + vv[b];
  }
}

// ---------------------------------------------------------------------------
extern "C" void kernel_launch(void* const* d_in, const int* in_sizes, int n_in,
                              void* d_out, int out_size, void* d_ws,
                              size_t ws_size, hipStream_t stream) {
  const float* states   = (const float*)d_in[0];
  const float* agent_qs = (const float*)d_in[1];
  const float* W1       = (const float*)d_in[2];
  const float* b1       = (const float*)d_in[3];
  const float* W2       = (const float*)d_in[4];
  const float* b2       = (const float*)d_in[5];
  const float* W3       = (const float*)d_in[6];
  const float* b3       = (const float*)d_in[7];
  const float* Vw1      = (const float*)d_in[8];
  const float* Vb1      = (const float*)d_in[9];
  const float* Vw2      = (const float*)d_in[10];
  const float* Vb2      = (const float*)d_in[11];
  float* out = (float*)d_out;

  char* ws = (char*)d_ws;
  float*  sW     = (float*)(ws);                     // 1 MB
  float*  vv     = (float*)(ws + 1048576);           // 4 KB
  __bf16* W1b_bf = (__bf16*)(ws + 1052672);          // 64 KB
  __bf16* W2_bf  = (__bf16*)(ws + 1118208);          // 128 KB

  prep_pack_kernel<<<560, 256, 0, stream>>>(states, W1, b1, W2, Vw1, Vb1,
                                            Vw2, Vb2, sW, vv, W1b_bf, W2_bf);
  main_kernel<<<B_TOT, 256, 0, stream>>>(agent_qs, b2, W3, b3, sW, vv,
                                         W1b_bf, W2_bf, out);
}

// Round 7
// 124.896 us; speedup vs baseline: 1.0725x; 1.0725x over previous
//
#include <hip/hip_runtime.h>

// SQDDPG mixer, MI355X. Round 7: revert main to R5 shape (4 blocks/CU won
// over halved L2 traffic in R6 — latency regime), and MFMA-ify prep:
// [W1top|Vw1] packed to B-frags, 64-block GEMM writes sW + atomic V partials.
//
// Frozen validated facts (R2/R3/R5 passes): threefry partitionable,
// bits=o0^o1, counter (0, b*128+n); stable ranks; coalition slot j <-
// qs[inv_l[j]]; output agent n reads prefix-row pos_l[n]; A-frag
// A[m=l15][k=t*32+q*8+j]; C-frag row=q*4+r col=l15; B-frag pack: slot
// (t,u,L) elem j -> B[k=t*32+(L>>4)*8+j][n=u*16+(L&15)].

#define A_N   8
#define NA_N  16
#define S_N   16
#define SD    256
#define EMB   256
#define B_TOT 1024

typedef __bf16 bf16x8 __attribute__((ext_vector_type(8)));
typedef float  f32x4  __attribute__((ext_vector_type(4)));

__device__ __forceinline__ f32x4 splat4(float v) {
  f32x4 x; x[0] = v; x[1] = v; x[2] = v; x[3] = v; return x;
}
__device__ __forceinline__ bf16x8 zero8() {
  bf16x8 z;
#pragma unroll
  for (int j = 0; j < 8; ++j) z[j] = (__bf16)0.0f;
  return z;
}

// ---------------------------------------------------------------------------
// JAX threefry2x32, key = (0, 42); partitionable draw: bits = o0 ^ o1.
// ---------------------------------------------------------------------------
__device__ __forceinline__ float jax_uniform(unsigned idx) {
  const unsigned ks0 = 0u, ks1 = 42u, ks2 = 0x1BD11BDAu ^ 42u;
  unsigned x0 = 0u + ks0;
  unsigned x1 = idx + ks1;
#define TF_RND(r) { x0 += x1; x1 = (x1 << (r)) | (x1 >> (32 - (r))); x1 ^= x0; }
  TF_RND(13) TF_RND(15) TF_RND(26) TF_RND(6)  x0 += ks1; x1 += ks2 + 1u;
  TF_RND(17) TF_RND(29) TF_RND(16) TF_RND(24) x0 += ks2; x1 += ks0 + 2u;
  TF_RND(13) TF_RND(15) TF_RND(26) TF_RND(6)  x0 += ks0; x1 += ks1 + 3u;
  TF_RND(17) TF_RND(29) TF_RND(16) TF_RND(24) x0 += ks1; x1 += ks2 + 4u;
  TF_RND(13) TF_RND(15) TF_RND(26) TF_RND(6)  x0 += ks2; x1 += ks0 + 5u;
#undef TF_RND
  const unsigned bits = x0 ^ x1;
  return __uint_as_float((bits >> 9) | 0x3F800000u) - 1.0f;
}

// ---------------------------------------------------------------------------
// Pack (112 blocks): W1bot (4096 slots), W2 (8192 slots), PW=[W1top|Vw1]
// (16384 slots, N=512 -> u=0..31) into bf16 B-fragment order.
// ---------------------------------------------------------------------------
__global__ __launch_bounds__(256) void pack_kernel(
    const float* __restrict__ W1, const float* __restrict__ W2,
    const float* __restrict__ Vw1, __bf16* __restrict__ W1b_bf,
    __bf16* __restrict__ W2_bf, __bf16* __restrict__ PW_bf) {
  const int ts = blockIdx.x * 256 + threadIdx.x;  // 0..28671
  if (ts < 4096) {                                // W1 bottom: t=0..3, u=0..15
    const int t = ts >> 10, rem = ts & 1023, u = rem >> 6, L = rem & 63;
    const int q = L >> 4, l15 = L & 15;
#pragma unroll
    for (int j = 0; j < 8; ++j) {
      const int k = t * 32 + q * 8 + j, nn = u * 16 + l15;
      W1b_bf[ts * 8 + j] = (__bf16)W1[(SD + k) * EMB + nn];
    }
  } else if (ts < 12288) {                        // W2: t=0..7, u=0..15
    const int ts2 = ts - 4096;
    const int t = ts2 >> 10, rem = ts2 & 1023, u = rem >> 6, L = rem & 63;
    const int q = L >> 4, l15 = L & 15;
#pragma unroll
    for (int j = 0; j < 8; ++j) {
      const int k = t * 32 + q * 8 + j, nn = u * 16 + l15;
      W2_bf[ts2 * 8 + j] = (__bf16)W2[k * EMB + nn];
    }
  } else {                                        // PW: t=0..7, u=0..31
    const int ts3 = ts - 12288;
    const int t = ts3 >> 11, rem = ts3 & 2047, u = rem >> 6, L = rem & 63;
    const int q = L >> 4, l15 = L & 15;
#pragma unroll
    for (int j = 0; j < 8; ++j) {
      const int k = t * 32 + q * 8 + j, nn = u * 16 + l15;  // nn in 0..511
      const float v = (nn < EMB) ? W1[k * EMB + nn]
                                 : Vw1[k * EMB + (nn - EMB)];
      PW_bf[ts3 * 8 + j] = (__bf16)v;
    }
  }
}

// ---------------------------------------------------------------------------
// Prep via MFMA: 64 blocks = 16 M-tiles (64 rows) x 4 N-strips (128 cols).
// C = st(1024x256) @ [W1top|Vw1](256x512) + [b1|Vb1].
// Strips 0,1 -> sW; strips 2,3 -> relu()*Vw2, reduce -> atomicAdd vv.
// ---------------------------------------------------------------------------
__global__ __launch_bounds__(256) void prep_mfma_kernel(
    const float* __restrict__ states, const float* __restrict__ b1,
    const float* __restrict__ Vb1, const float* __restrict__ Vw2,
    const __bf16* __restrict__ PW_bf, float* __restrict__ sW,
    float* __restrict__ vv) {
  const int mi = blockIdx.x >> 2;   // 0..15
  const int ni = blockIdx.x & 3;    // 0..3
  const int n = threadIdx.x;
  const int w = n >> 6, L = n & 63, q = L >> 4, l15 = L & 15;

  f32x4 acc[4][2];
#pragma unroll
  for (int ui = 0; ui < 2; ++ui) {
    const int col = (ni * 8 + w * 2 + ui) * 16 + l15;  // 0..511
    const float bias = (col < EMB) ? b1[col] : Vb1[col - EMB];
#pragma unroll
    for (int mt = 0; mt < 4; ++mt) acc[mt][ui] = splat4(bias);
  }

#pragma unroll 2
  for (int t = 0; t < 8; ++t) {
    bf16x8 bfr[2];
#pragma unroll
    for (int ui = 0; ui < 2; ++ui) {
      const int u = ni * 8 + w * 2 + ui;
      bfr[ui] = *(const bf16x8*)&PW_bf[((t * 32 + u) * 64 + L) * 8];
    }
#pragma unroll
    for (int mt = 0; mt < 4; ++mt) {
      const float* srow = &states[(mi * 64 + mt * 16 + l15) * SD + t * 32 + q * 8];
      bf16x8 af;
#pragma unroll
      for (int j = 0; j < 8; ++j) af[j] = (__bf16)srow[j];
#pragma unroll
      for (int ui = 0; ui < 2; ++ui)
        acc[mt][ui] = __builtin_amdgcn_mfma_f32_16x16x32_bf16(
            af, bfr[ui], acc[mt][ui], 0, 0, 0);
    }
  }

  if (ni < 2) {
    // sW strips: C row = mi*64+mt*16+q*4+r, col = ucol*16+l15
#pragma unroll
    for (int ui = 0; ui < 2; ++ui) {
      const int col = (ni * 8 + w * 2 + ui) * 16 + l15;
#pragma unroll
      for (int mt = 0; mt < 4; ++mt)
#pragma unroll
        for (int r = 0; r < 4; ++r)
          sW[(mi * 64 + mt * 16 + q * 4 + r) * EMB + col] = acc[mt][ui][r];
    }
  } else {
    // V strips: relu * Vw2, reduce over 16 cols, atomic into vv[row]
#pragma unroll
    for (int mt = 0; mt < 4; ++mt) {
#pragma unroll
      for (int r = 0; r < 4; ++r) {
        float p = 0.f;
#pragma unroll
        for (int ui = 0; ui < 2; ++ui) {
          const int colV = (ni * 8 + w * 2 + ui) * 16 + l15 - EMB;
          p = fmaf(fmaxf(acc[mt][ui][r], 0.f), Vw2[colV], p);
        }
#pragma unroll
        for (int off = 1; off < 16; off <<= 1) p += __shfl_xor(p, off);
        if (l15 == 0)
          atomicAdd(&vv[mi * 64 + mt * 16 + q * 4 + r], p);
      }
    }
  }
}

// ---------------------------------------------------------------------------
// Main: 1024 blocks (one per b), 256 threads = 4 waves. Two passes of M=64.
// R5 structure verbatim (proven): acc[4][2] live, (256,4), 36 KB LDS.
// ---------------------------------------------------------------------------
__global__ __launch_bounds__(256, 4) void main_kernel(
    const float* __restrict__ agent_qs, const float* __restrict__ b2g,
    const float* __restrict__ W3, const float* __restrict__ b3,
    const float* __restrict__ Vb2, const float* __restrict__ sW,
    const float* __restrict__ vv, const __bf16* __restrict__ W1b_bf,
    const __bf16* __restrict__ W2_bf, float* __restrict__ out) {
  __shared__ bf16x8 h1_l[32 * 64];      // 32 KB: layer2 A-frags (M=64,K=256)
  __shared__ __attribute__((aligned(16))) __bf16 qs_bf[A_N * NA_N];
  __shared__ float u_l[128];
  __shared__ int   inv_l[128];          // inv_l[s*8+a] = rank of agent a
  __shared__ int   pos_l[128];          // pos_l[s*8+r] = agent with rank r
  __shared__ float adv_part[4][64];
  __shared__ float marg_l[128];         // marginal[s*8 + prefix-row]

  const int b = blockIdx.x;
  const int n = threadIdx.x;
  const int w = n >> 6, L = n & 63, q = L >> 4, l15 = L & 15;

  if (n < 128) {
    qs_bf[n] = (__bf16)agent_qs[b * 128 + n];
    u_l[n] = jax_uniform((unsigned)(b * 128 + n));
  }
  __syncthreads();

  if (n < 128) {
    const int s = n >> 3, a = n & 7;
    const float u = u_l[n];
    int r = 0;
#pragma unroll
    for (int a2 = 0; a2 < A_N; ++a2) {
      const float u2 = u_l[s * 8 + a2];
      r += (u2 < u || (u2 == u && a2 < a)) ? 1 : 0;
    }
    inv_l[n] = r;
    pos_l[s * 8 + r] = a;
  }
  __syncthreads();

  const int i_pref  = l15 & 7;     // prefix length of this lane's A-row
  const int sl_half = l15 >> 3;    // which s within the mt pair
  const int jq      = q >> 1;      // jcoal low bit
  const int na0     = (q & 1) * 8; // action sub-block

  for (int p = 0; p < 2; ++p) {
    // ---- layer 1: (64x128) @ W1b (128x256), C init sW[col]; 2 un-halves --
#pragma unroll 1
    for (int nh = 0; nh < 2; ++nh) {
      f32x4 acc[4][2];
#pragma unroll
      for (int i = 0; i < 2; ++i) {
        const float sv = sW[b * EMB + (w * 4 + nh * 2 + i) * 16 + l15];
#pragma unroll
        for (int mt = 0; mt < 4; ++mt) acc[mt][i] = splat4(sv);
      }
#pragma unroll 2
      for (int t = 0; t < 4; ++t) {
        const int jcoal = t * 2 + jq;
        const bool on = (jcoal <= i_pref);
        bf16x8 bfr[2];
#pragma unroll
        for (int i = 0; i < 2; ++i)
          bfr[i] = *(const bf16x8*)
              &W1b_bf[((t * 16 + w * 4 + nh * 2 + i) * 64 + L) * 8];
#pragma unroll
        for (int mt = 0; mt < 4; ++mt) {
          const int ag = inv_l[(p * 8 + mt * 2 + sl_half) * 8 + jcoal];
          const bf16x8 qv = *(const bf16x8*)&qs_bf[ag * NA_N + na0];
          const bf16x8 af = on ? qv : zero8();
#pragma unroll
          for (int i = 0; i < 2; ++i)
            acc[mt][i] = __builtin_amdgcn_mfma_f32_16x16x32_bf16(
                af, bfr[i], acc[mt][i], 0, 0, 0);
        }
      }
      // relu -> bf16 scatter into layer2 A-frag layout (frozen formula)
      __bf16* h1e = (__bf16*)h1_l;
#pragma unroll
      for (int i = 0; i < 2; ++i) {
        const int c = (w * 4 + nh * 2 + i) * 16 + l15;
        const int t2 = c >> 5, q2 = (c >> 3) & 3, j2 = l15 & 7;
#pragma unroll
        for (int mt = 0; mt < 4; ++mt) {
#pragma unroll
          for (int r = 0; r < 4; ++r) {
            const float v = fmaxf(acc[mt][i][r], 0.f);
            h1e[(((t2 * 4 + mt) * 64) + q2 * 16 + q * 4 + r) * 8 + j2] =
                (__bf16)v;
          }
        }
      }
    }
    __syncthreads();

    // ---- layer 2 + layer 3 partials: 2 un-halves, psum across halves ----
    float psum[4][4];
#pragma unroll
    for (int mt = 0; mt < 4; ++mt)
#pragma unroll
      for (int r = 0; r < 4; ++r) psum[mt][r] = 0.f;

#pragma unroll 1
    for (int nh = 0; nh < 2; ++nh) {
      f32x4 acc[4][2];
#pragma unroll
      for (int i = 0; i < 2; ++i) {
        const float bv = b2g[(w * 4 + nh * 2 + i) * 16 + l15];
#pragma unroll
        for (int mt = 0; mt < 4; ++mt) acc[mt][i] = splat4(bv);
      }
#pragma unroll 2
      for (int t = 0; t < 8; ++t) {
        bf16x8 bfr[2];
#pragma unroll
        for (int i = 0; i < 2; ++i)
          bfr[i] = *(const bf16x8*)
              &W2_bf[((t * 16 + w * 4 + nh * 2 + i) * 64 + L) * 8];
#pragma unroll
        for (int mt = 0; mt < 4; ++mt) {
          const bf16x8 af = h1_l[(t * 4 + mt) * 64 + L];
#pragma unroll
          for (int i = 0; i < 2; ++i)
            acc[mt][i] = __builtin_amdgcn_mfma_f32_16x16x32_bf16(
                af, bfr[i], acc[mt][i], 0, 0, 0);
        }
      }
#pragma unroll
      for (int i = 0; i < 2; ++i) {
        const float w3v = W3[(w * 4 + nh * 2 + i) * 16 + l15];
#pragma unroll
        for (int mt = 0; mt < 4; ++mt)
#pragma unroll
          for (int r = 0; r < 4; ++r)
            psum[mt][r] = fmaf(fmaxf(acc[mt][i][r], 0.f), w3v, psum[mt][r]);
      }
    }

    // ---- reduce 16 cols per quad, combine waves via LDS ----
#pragma unroll
    for (int mt = 0; mt < 4; ++mt) {
#pragma unroll
      for (int r = 0; r < 4; ++r) {
        float sum = psum[mt][r];
#pragma unroll
        for (int off = 1; off < 16; off <<= 1) sum += __shfl_xor(sum, off);
        if (l15 == 0) adv_part[w][mt * 16 + q * 4 + r] = sum;
      }
    }
    __syncthreads();
    if (n < 64)
      marg_l[p * 64 + n] = adv_part[0][n] + adv_part[1][n] +
                           adv_part[2][n] + adv_part[3][n];
    __syncthreads();
  }

  // ---- gather: agent a reads prefix-row pos_l[s*8+a] (validated) ----
  if (n < A_N) {
    float sh = 0.f;
#pragma unroll
    for (int s = 0; s < S_N; ++s) sh += marg_l[s * 8 + pos_l[s * 8 + n]];
    out[b * A_N + n] = sh * (1.f / 16.f) + b3[0] + Vb2[0] + vv[b];
  }
}

// ---------------------------------------------------------------------------
extern "C" void kernel_launch(void* const* d_in, const int* in_sizes, int n_in,
                              void* d_out, int out_size, void* d_ws,
                              size_t ws_size, hipStream_t stream) {
  const float* states   = (const float*)d_in[0];
  const float* agent_qs = (const float*)d_in[1];
  const float* W1       = (const float*)d_in[2];
  const float* b1       = (const float*)d_in[3];
  const float* W2       = (const float*)d_in[4];
  const float* b2       = (const float*)d_in[5];
  const float* W3       = (const float*)d_in[6];
  const float* b3       = (const float*)d_in[7];
  const float* Vw1      = (const float*)d_in[8];
  const float* Vb1      = (const float*)d_in[9];
  const float* Vw2      = (const float*)d_in[10];
  const float* Vb2      = (const float*)d_in[11];
  float* out = (float*)d_out;

  char* ws = (char*)d_ws;
  float*  sW     = (float*)(ws);                     // 1 MB
  float*  vv     = (float*)(ws + 1048576);           // 4 KB
  __bf16* W1b_bf = (__bf16*)(ws + 1052672);          // 64 KB
  __bf16* W2_bf  = (__bf16*)(ws + 1118208);          // 128 KB
  __bf16* PW_bf  = (__bf16*)(ws + 1249280);          // 256 KB

  hipMemsetAsync(vv, 0, B_TOT * sizeof(float), stream);
  pack_kernel<<<112, 256, 0, stream>>>(W1, W2, Vw1, W1b_bf, W2_bf, PW_bf);
  prep_mfma_kernel<<<64, 256, 0, stream>>>(states, b1, Vb1, Vw2, PW_bf,
                                           sW, vv);
  main_kernel<<<B_TOT, 256, 0, stream>>>(agent_qs, b2, W3, b3, Vb2, sW, vv,
                                         W1b_bf, W2_bf, out);
}

// Round 8
// 123.879 us; speedup vs baseline: 1.0813x; 1.0082x over previous
//
#include <hip/hip_runtime.h>

// SQDDPG mixer, MI355X. Round 8: 2 launches (pack+prep fused, no memset via
// vpart split), main barrier diet (defer adv reduce, no marg_l), hoisted
// per-column constants. Main MFMA structure = R5/R7 (proven 4 blocks/CU).
//
// Frozen validated facts (R2/R3/R5/R7 passes): threefry partitionable,
// bits=o0^o1, counter (0, b*128+n); stable ranks; coalition slot j <-
// qs[inv_l[j]]; output agent n reads prefix-row pos_l[n]; A-frag
// A[m=l15][k=t*32+q*8+j]; C-frag row=q*4+r col=l15; B-frag pack: slot
// (t,u,L) elem j -> B[k=t*32+(L>>4)*8+j][n=u*16+(L&15)].

#define A_N   8
#define NA_N  16
#define S_N   16
#define SD    256
#define EMB   256
#define B_TOT 1024

typedef __bf16 bf16x8 __attribute__((ext_vector_type(8)));
typedef float  f32x4  __attribute__((ext_vector_type(4)));

__device__ __forceinline__ f32x4 splat4(float v) {
  f32x4 x; x[0] = v; x[1] = v; x[2] = v; x[3] = v; return x;
}
__device__ __forceinline__ bf16x8 zero8() {
  bf16x8 z;
#pragma unroll
  for (int j = 0; j < 8; ++j) z[j] = (__bf16)0.0f;
  return z;
}

// ---------------------------------------------------------------------------
// JAX threefry2x32, key = (0, 42); partitionable draw: bits = o0 ^ o1.
// ---------------------------------------------------------------------------
__device__ __forceinline__ float jax_uniform(unsigned idx) {
  const unsigned ks0 = 0u, ks1 = 42u, ks2 = 0x1BD11BDAu ^ 42u;
  unsigned x0 = 0u + ks0;
  unsigned x1 = idx + ks1;
#define TF_RND(r) { x0 += x1; x1 = (x1 << (r)) | (x1 >> (32 - (r))); x1 ^= x0; }
  TF_RND(13) TF_RND(15) TF_RND(26) TF_RND(6)  x0 += ks1; x1 += ks2 + 1u;
  TF_RND(17) TF_RND(29) TF_RND(16) TF_RND(24) x0 += ks2; x1 += ks0 + 2u;
  TF_RND(13) TF_RND(15) TF_RND(26) TF_RND(6)  x0 += ks0; x1 += ks1 + 3u;
  TF_RND(17) TF_RND(29) TF_RND(16) TF_RND(24) x0 += ks1; x1 += ks2 + 4u;
  TF_RND(13) TF_RND(15) TF_RND(26) TF_RND(6)  x0 += ks2; x1 += ks0 + 5u;
#undef TF_RND
  const unsigned bits = x0 ^ x1;
  return __uint_as_float((bits >> 9) | 0x3F800000u) - 1.0f;
}

// ---------------------------------------------------------------------------
// One launch: blocks 0..47 pack W1b_bf + W2_bf; blocks 48..111 = MFMA prep
// (16 M-tiles x 4 N-strips of [W1top|Vw1], B-frags built on the fly).
// Strips 0,1 -> sW; strips 2,3 -> relu()*Vw2 reduced -> vpart[ni-2][row].
// ---------------------------------------------------------------------------
__global__ __launch_bounds__(256) void prep_pack_kernel(
    const float* __restrict__ states, const float* __restrict__ W1,
    const float* __restrict__ b1, const float* __restrict__ W2,
    const float* __restrict__ Vw1, const float* __restrict__ Vb1,
    const float* __restrict__ Vw2, float* __restrict__ sW,
    float* __restrict__ vpart, __bf16* __restrict__ W1b_bf,
    __bf16* __restrict__ W2_bf) {
  const int n = threadIdx.x;

  if (blockIdx.x < 48) {
    // ---- pack path: bf16 B-fragment order (frozen formula) ----
    const int ts = blockIdx.x * 256 + n;            // 0..12287
    if (ts < 4096) {                                // W1 bottom: t=0..3
      const int t = ts >> 10, rem = ts & 1023, u = rem >> 6, L = rem & 63;
      const int q = L >> 4, l15 = L & 15;
#pragma unroll
      for (int j = 0; j < 8; ++j) {
        const int k = t * 32 + q * 8 + j, nn = u * 16 + l15;
        W1b_bf[ts * 8 + j] = (__bf16)W1[(SD + k) * EMB + nn];
      }
    } else {                                        // W2: t=0..7
      const int ts2 = ts - 4096;
      const int t = ts2 >> 10, rem = ts2 & 1023, u = rem >> 6, L = rem & 63;
      const int q = L >> 4, l15 = L & 15;
#pragma unroll
      for (int j = 0; j < 8; ++j) {
        const int k = t * 32 + q * 8 + j, nn = u * 16 + l15;
        W2_bf[ts2 * 8 + j] = (__bf16)W2[k * EMB + nn];
      }
    }
    return;
  }

  // ---- prep path ----
  __shared__ float vred[4][64];
  const int blk = blockIdx.x - 48;  // 0..63
  const int mi = blk >> 2;          // 0..15
  const int ni = blk & 3;           // 0..3
  const int w = n >> 6, L = n & 63, q = L >> 4, l15 = L & 15;

  f32x4 acc[4][2];
#pragma unroll
  for (int ui = 0; ui < 2; ++ui) {
    const int col = (ni * 8 + w * 2 + ui) * 16 + l15;  // 0..511
    const float bias = (col < EMB) ? b1[col] : Vb1[col - EMB];
#pragma unroll
    for (int mt = 0; mt < 4; ++mt) acc[mt][ui] = splat4(bias);
  }

#pragma unroll 2
  for (int t = 0; t < 8; ++t) {
    bf16x8 bfr[2];
#pragma unroll
    for (int ui = 0; ui < 2; ++ui) {
      const int nn = (ni * 8 + w * 2 + ui) * 16 + l15;  // 0..511
#pragma unroll
      for (int j = 0; j < 8; ++j) {
        const int k = t * 32 + q * 8 + j;
        const float v = (nn < EMB) ? W1[k * EMB + nn]
                                   : Vw1[k * EMB + (nn - EMB)];
        bfr[ui][j] = (__bf16)v;
      }
    }
#pragma unroll
    for (int mt = 0; mt < 4; ++mt) {
      const float* srow =
          &states[(mi * 64 + mt * 16 + l15) * SD + t * 32 + q * 8];
      bf16x8 af;
#pragma unroll
      for (int j = 0; j < 8; ++j) af[j] = (__bf16)srow[j];
#pragma unroll
      for (int ui = 0; ui < 2; ++ui)
        acc[mt][ui] = __builtin_amdgcn_mfma_f32_16x16x32_bf16(
            af, bfr[ui], acc[mt][ui], 0, 0, 0);
    }
  }

  if (ni < 2) {
    // sW strips: C row = mi*64+mt*16+q*4+r, col = u*16+l15
#pragma unroll
    for (int ui = 0; ui < 2; ++ui) {
      const int col = (ni * 8 + w * 2 + ui) * 16 + l15;
#pragma unroll
      for (int mt = 0; mt < 4; ++mt)
#pragma unroll
        for (int r = 0; r < 4; ++r)
          sW[(mi * 64 + mt * 16 + q * 4 + r) * EMB + col] = acc[mt][ui][r];
    }
  } else {
    // V strips: relu * Vw2, 16-col shuffle reduce, LDS-combine the 4 waves,
    // then deterministic write to vpart[(ni-2)*B_TOT + row] (no atomics).
#pragma unroll
    for (int mt = 0; mt < 4; ++mt) {
#pragma unroll
      for (int r = 0; r < 4; ++r) {
        float p = 0.f;
#pragma unroll
        for (int ui = 0; ui < 2; ++ui) {
          const int colV = (ni * 8 + w * 2 + ui) * 16 + l15 - EMB;
          p = fmaf(fmaxf(acc[mt][ui][r], 0.f), Vw2[colV], p);
        }
#pragma unroll
        for (int off = 1; off < 16; off <<= 1) p += __shfl_xor(p, off);
        if (l15 == 0) vred[w][mt * 16 + q * 4 + r] = p;
      }
    }
    __syncthreads();
    if (n < 64)
      vpart[(ni - 2) * B_TOT + mi * 64 + n] =
          vred[0][n] + vred[1][n] + vred[2][n] + vred[3][n];
  }
}

// ---------------------------------------------------------------------------
// Main: 1024 blocks (one per b), 256 threads = 4 waves. Two passes of M=64.
// R5 MFMA structure; deferred adv reduction (6 syncs, no marg_l).
// ---------------------------------------------------------------------------
__global__ __launch_bounds__(256, 4) void main_kernel(
    const float* __restrict__ agent_qs, const float* __restrict__ b2g,
    const float* __restrict__ W3, const float* __restrict__ b3,
    const float* __restrict__ Vb2, const float* __restrict__ sW,
    const float* __restrict__ vpart, const __bf16* __restrict__ W1b_bf,
    const __bf16* __restrict__ W2_bf, float* __restrict__ out) {
  __shared__ bf16x8 h1_l[32 * 64];      // 32 KB: layer2 A-frags (M=64,K=256)
  __shared__ __attribute__((aligned(16))) __bf16 qs_bf[A_N * NA_N];
  __shared__ float u_l[128];
  __shared__ int   inv_l[128];          // inv_l[s*8+a] = rank of agent a
  __shared__ int   pos_l[128];          // pos_l[s*8+r] = agent with rank r
  __shared__ float adv_part[4][128];    // [wave][p*64 + row]

  const int b = blockIdx.x;
  const int n = threadIdx.x;
  const int w = n >> 6, L = n & 63, q = L >> 4, l15 = L & 15;

  if (n < 128) {
    qs_bf[n] = (__bf16)agent_qs[b * 128 + n];
    u_l[n] = jax_uniform((unsigned)(b * 128 + n));
  }
  // hoisted per-column constants (cols c = (w*4+j)*16 + l15, j=nh*2+i)
  float sWv[4], b2v[4], w3v[4];
#pragma unroll
  for (int j = 0; j < 4; ++j) {
    const int c = (w * 4 + j) * 16 + l15;
    sWv[j] = sW[b * EMB + c];
    b2v[j] = b2g[c];
    w3v[j] = W3[c];
  }
  __syncthreads();

  if (n < 128) {
    const int s = n >> 3, a = n & 7;
    const float u = u_l[n];
    int r = 0;
#pragma unroll
    for (int a2 = 0; a2 < A_N; ++a2) {
      const float u2 = u_l[s * 8 + a2];
      r += (u2 < u || (u2 == u && a2 < a)) ? 1 : 0;
    }
    inv_l[n] = r;
    pos_l[s * 8 + r] = a;
  }
  __syncthreads();

  const int i_pref  = l15 & 7;     // prefix length of this lane's A-row
  const int sl_half = l15 >> 3;    // which s within the mt pair
  const int jq      = q >> 1;      // jcoal low bit
  const int na0     = (q & 1) * 8; // action sub-block

  for (int p = 0; p < 2; ++p) {
    // ---- layer 1: (64x128) @ W1b (128x256), C init sW[col]; 2 un-halves --
#pragma unroll 1
    for (int nh = 0; nh < 2; ++nh) {
      f32x4 acc[4][2];
#pragma unroll
      for (int i = 0; i < 2; ++i) {
#pragma unroll
        for (int mt = 0; mt < 4; ++mt) acc[mt][i] = splat4(sWv[nh * 2 + i]);
      }
#pragma unroll 2
      for (int t = 0; t < 4; ++t) {
        const int jcoal = t * 2 + jq;
        const bool on = (jcoal <= i_pref);
        bf16x8 bfr[2];
#pragma unroll
        for (int i = 0; i < 2; ++i)
          bfr[i] = *(const bf16x8*)
              &W1b_bf[((t * 16 + w * 4 + nh * 2 + i) * 64 + L) * 8];
#pragma unroll
        for (int mt = 0; mt < 4; ++mt) {
          const int ag = inv_l[(p * 8 + mt * 2 + sl_half) * 8 + jcoal];
          const bf16x8 qv = *(const bf16x8*)&qs_bf[ag * NA_N + na0];
          const bf16x8 af = on ? qv : zero8();
#pragma unroll
          for (int i = 0; i < 2; ++i)
            acc[mt][i] = __builtin_amdgcn_mfma_f32_16x16x32_bf16(
                af, bfr[i], acc[mt][i], 0, 0, 0);
        }
      }
      // relu -> bf16 scatter into layer2 A-frag layout (frozen formula)
      __bf16* h1e = (__bf16*)h1_l;
#pragma unroll
      for (int i = 0; i < 2; ++i) {
        const int c = (w * 4 + nh * 2 + i) * 16 + l15;
        const int t2 = c >> 5, q2 = (c >> 3) & 3, j2 = l15 & 7;
#pragma unroll
        for (int mt = 0; mt < 4; ++mt) {
#pragma unroll
          for (int r = 0; r < 4; ++r) {
            const float v = fmaxf(acc[mt][i][r], 0.f);
            h1e[(((t2 * 4 + mt) * 64) + q2 * 16 + q * 4 + r) * 8 + j2] =
                (__bf16)v;
          }
        }
      }
    }
    __syncthreads();  // h1 visible to all waves

    // ---- layer 2 + layer 3 partials: 2 un-halves, psum across halves ----
    float psum[4][4];
#pragma unroll
    for (int mt = 0; mt < 4; ++mt)
#pragma unroll
      for (int r = 0; r < 4; ++r) psum[mt][r] = 0.f;

#pragma unroll 1
    for (int nh = 0; nh < 2; ++nh) {
      f32x4 acc[4][2];
#pragma unroll
      for (int i = 0; i < 2; ++i) {
#pragma unroll
        for (int mt = 0; mt < 4; ++mt) acc[mt][i] = splat4(b2v[nh * 2 + i]);
      }
#pragma unroll 2
      for (int t = 0; t < 8; ++t) {
        bf16x8 bfr[2];
#pragma unroll
        for (int i = 0; i < 2; ++i)
          bfr[i] = *(const bf16x8*)
              &W2_bf[((t * 16 + w * 4 + nh * 2 + i) * 64 + L) * 8];
#pragma unroll
        for (int mt = 0; mt < 4; ++mt) {
          const bf16x8 af = h1_l[(t * 4 + mt) * 64 + L];
#pragma unroll
          for (int i = 0; i < 2; ++i)
            acc[mt][i] = __builtin_amdgcn_mfma_f32_16x16x32_bf16(
                af, bfr[i], acc[mt][i], 0, 0, 0);
        }
      }
#pragma unroll
      for (int i = 0; i < 2; ++i) {
#pragma unroll
        for (int mt = 0; mt < 4; ++mt)
#pragma unroll
          for (int r = 0; r < 4; ++r)
            psum[mt][r] = fmaf(fmaxf(acc[mt][i][r], 0.f), w3v[nh * 2 + i],
                               psum[mt][r]);
      }
    }

    // ---- 16-col shuffle reduce; per-wave partials, combine deferred ----
#pragma unroll
    for (int mt = 0; mt < 4; ++mt) {
#pragma unroll
      for (int r = 0; r < 4; ++r) {
        float sum = psum[mt][r];
#pragma unroll
        for (int off = 1; off < 16; off <<= 1) sum += __shfl_xor(sum, off);
        if (l15 == 0) adv_part[w][p * 64 + mt * 16 + q * 4 + r] = sum;
      }
    }
    __syncthreads();  // adv_part done; h1 safe to overwrite next pass
  }

  // ---- gather: agent a reads prefix-row pos_l[s*8+a], sums 4 waves ----
  if (n < A_N) {
    float sh = 0.f;
#pragma unroll
    for (int s = 0; s < S_N; ++s) {
      const int idx = (s >> 3) * 64 + (s & 7) * 8 + pos_l[s * 8 + n];
      sh += adv_part[0][idx] + adv_part[1][idx] +
            adv_part[2][idx] + adv_part[3][idx];
    }
    out[b * A_N + n] = sh * (1.f / 16.f) + b3[0] + Vb2[0] +
                       vpart[b] + vpart[B_TOT + b];
  }
}

// ---------------------------------------------------------------------------
extern "C" void kernel_launch(void* const* d_in, const int* in_sizes, int n_in,
                              void* d_out, int out_size, void* d_ws,
                              size_t ws_size, hipStream_t stream) {
  const float* states   = (const float*)d_in[0];
  const float* agent_qs = (const float*)d_in[1];
  const float* W1       = (const float*)d_in[2];
  const float* b1       = (const float*)d_in[3];
  const float* W2       = (const float*)d_in[4];
  const float* b2       = (const float*)d_in[5];
  const float* W3       = (const float*)d_in[6];
  const float* b3       = (const float*)d_in[7];
  const float* Vw1      = (const float*)d_in[8];
  const float* Vb1      = (const float*)d_in[9];
  const float* Vw2      = (const float*)d_in[10];
  const float* Vb2      = (const float*)d_in[11];
  float* out = (float*)d_out;

  char* ws = (char*)d_ws;
  float*  sW     = (float*)(ws);                     // 1 MB
  float*  vpart  = (float*)(ws + 1048576);           // 2 x 4 KB
  __bf16* W1b_bf = (__bf16*)(ws + 1057792);          // 64 KB
  __bf16* W2_bf  = (__bf16*)(ws + 1123328);          // 128 KB

  prep_pack_kernel<<<112, 256, 0, stream>>>(states, W1, b1, W2, Vw1, Vb1,
                                            Vw2, sW, vpart, W1b_bf, W2_bf);
  main_kernel<<<B_TOT, 256, 0, stream>>>(agent_qs, b2, W3, b3, Vb2, sW,
                                         vpart, W1b_bf, W2_bf, out);
}